// Round 7
// baseline (377.843 us; speedup 1.0000x reference)
//
#include <hip/hip_runtime.h>
#include <hip/hip_bf16.h>
#include <math.h>

// ---------------- constants ----------------
#define BATCH   16
#define TFRM    4096          // frames per batch (= L)
#define DIM     512
#define ODIM    1026
#define KP      513           // ODIM/2
#define NFFT    1024
#define HOP     256
#define PADC    384           // (WIN-HOP)/2
#define MROWS   (BATCH*TFRM)  // 65536
#define NPAD    1152          // h stride (= GEMM2 K), multiple of 32
#define WROWS   1280          // GEMM1 logical N, multiple of 256
#define OUTLEN  1048576       // per-batch output samples
#define TWO_PI_OVER_N 0.006135923151542565f  // 2*pi/1024
#define INV_TWO_PI    0.15915494309189535f   // 1/(2*pi)

typedef __bf16 bf16x8 __attribute__((ext_vector_type(8)));
typedef float  f32x4  __attribute__((ext_vector_type(4)));

__device__ __forceinline__ ushort f2bf(float f) {
  union { float f; unsigned u; } v; v.f = f;
  unsigned u = v.u;
  unsigned r = (u + 0x7FFFu + ((u >> 16) & 1u)) >> 16;
  return (ushort)r;
}
__device__ __forceinline__ float bf2f(ushort h) {
  union { unsigned u; float f; } v; v.u = ((unsigned)h) << 16;
  return v.f;
}
// HW transcendentals (single VALU op each; v_sin/v_cos take revolutions).
__device__ __forceinline__ float fast_sin(float x) { return __builtin_amdgcn_sinf(x * INV_TWO_PI); }
__device__ __forceinline__ float fast_cos(float x) { return __builtin_amdgcn_cosf(x * INV_TWO_PI); }
__device__ __forceinline__ float fast_exp(float x) { return __builtin_amdgcn_exp2f(x * 1.4426950408889634f); }

#define BAR() do { asm volatile("" ::: "memory"); __builtin_amdgcn_s_barrier(); \
                   asm volatile("" ::: "memory"); } while (0)

// ---------------- prep: x fp32 -> bf16 ----------------
__global__ void k_prep_x(const float4* __restrict__ x, ushort4* __restrict__ o, int n4) {
  int i = blockIdx.x * blockDim.x + threadIdx.x;
  int stride = gridDim.x * blockDim.x;
  for (; i < n4; i += stride) {
    float4 v = x[i];
    ushort4 r;
    r.x = f2bf(v.x); r.y = f2bf(v.y); r.z = f2bf(v.z); r.w = f2bf(v.w);
    o[i] = r;
  }
}

// ---------------- prep: W fp32 [1026][512] -> bf16 COLUMN-PERMUTED padded [1280][512]
// Row j (= h column j): j=2k -> orig mag row k; j=2k+1 -> orig phase row 513+k.
__global__ void k_prep_w(const float* __restrict__ W, ushort* __restrict__ o) {
  int i = blockIdx.x * 256 + threadIdx.x;          // over 1280*512
  if (i >= WROWS * DIM) return;
  int r = i >> 9;
  int c = i & 511;
  ushort v = 0;
  if (r < ODIM) {
    int orig = (r >> 1) + (r & 1) * KP;
    v = f2bf(W[orig * DIM + c]);
  }
  o[i] = v;
}

// ---------------- basis: BasisT[n][j] bf16, interleaved (a,b) layout, stride NPAD ----------------
// frames[n] = win[n]/1024 * ( a0 + a512*(-1)^n + 2*sum_{k=1}^{511}(a_k cos - b_k sin) )
__global__ void k_basis(ushort* __restrict__ bas) {
  int n = blockIdx.x;
  float wn = 0.5f - 0.5f * cosf((float)n * TWO_PI_OVER_N);
  float sc = wn * (1.0f / 1024.0f);
  for (int j = threadIdx.x; j < NPAD; j += 256) {
    float v = 0.0f;
    if (j < ODIM) {
      int k = j >> 1;
      int r = (k * n) & 1023;                      // exact integer phase reduction
      if ((j & 1) == 0) {
        float c = cosf((float)r * TWO_PI_OVER_N);
        v = ((k == 0 || k == 512) ? 1.0f : 2.0f) * c;
      } else if (k != 0 && k != 512) {
        v = -2.0f * sinf((float)r * TWO_PI_OVER_N);
      }
    }
    bas[n * NPAD + j] = f2bf(v * sc);
  }
}

// ---------------- GEMM: C[m][n] = sum_k A[m][k]*Bt[n][k]  (bf16 in, fp32 acc)
// 256x256 tile, BK=32, 8 waves (2M x 4N), 512 threads, ring of 4 LDS K-tile slots.
// m201-style fine-phase schedule: iteration = 2 K-tiles (u,v), 4 phases, each phase:
//   { ds_reads for THIS phase's MFMA; 2 global_load_lds (A- or B-half of a tile 3-4
//     ahead); s_barrier; lgkmcnt(0); setprio(1); 16 MFMA; setprio(0);
//     [counted vmcnt only at phases 2 & 4]; s_barrier }
// The 2-barrier-per-phase pattern creates the wave role-split on each SIMD (one wave
// in prio-1 MFMA while its SIMD-mate drains ds_reads) that makes the interleave pay.
// vmcnt FIFO audit (4 loads per tile, issue order = tile order):
//   P1-end vmcnt(8): 8 newest = tiles {u+3, u+2} -> tile u+1 (=v, read at P2) landed.
//   P3-end vmcnt(8): 8 newest = tiles {u+4, u+3} -> tile u+2 (next-iter u) landed.
//   Tail iter (stages only NK-1): P3-end vmcnt(4); last iter: P1-end vmcnt(0).
// Granule-XOR LDS swizzle (inverse-swizzled global source + swizzled ds_read) keeps
// bank conflicts at 0. XCD-chunked block swizzle. Requires NK even, NK >= 6.
// EPI=1: fused ISTFT-head activation on interleaved (mag,phase) columns.
template<int EPI>
__global__ __launch_bounds__(512, 2) void k_gemm(const ushort* __restrict__ A, int lda,
                                                 const ushort* __restrict__ Bt, int ldb,
                                                 ushort* __restrict__ C, int ldc,
                                                 int nbn, int NK, int ncol,
                                                 const float* __restrict__ bias) {
  // 4 slots x (A 256x32 + B 256x32) ushorts = 128 KiB
  __shared__ ushort lds[4][2][8192];
  const int tid  = threadIdx.x;
  const int cpx  = gridDim.x >> 3;
  const int bid  = (blockIdx.x & 7) * cpx + (blockIdx.x >> 3);   // XCD-chunked
  const int bm   = bid / nbn;
  const int bn   = bid - bm * nbn;
  const int lane = tid & 63;
  const int wv   = tid >> 6;
  const int wr   = (wv >> 2) * 128;    // wave M-offset (2 M-halves)
  const int wc   = (wv & 3) * 64;      // wave N-offset (4 N-quarters)
  const int fr   = lane & 15;
  const int gq   = lane >> 4;          // K-granule of the fragment (0..3)

  // ---- staging (thread i covers granule i and i+512 of each 256x32 tile) ----
  // LDS written linearly by global_load_lds; swizzle realized by permuting the GLOBAL
  // source granule: gcol = (i&3) ^ ((i>>3)&3)  (= (i&3) ^ ((row>>1)&3)).
  const int swz  = ((tid & 3) ^ ((tid >> 3) & 3)) << 3;          // ushort offset
  const ushort* gA0 = A  + (size_t)(bm * 256 + (tid >> 2)) * lda + swz;
  const ushort* gA1 = gA0 + (size_t)128 * lda;
  const ushort* gB0 = Bt + (size_t)(bn * 256 + (tid >> 2)) * ldb + swz;
  const ushort* gB1 = gB0 + (size_t)128 * ldb;
  const int lofs = (tid & 448) * 8;    // wave-uniform LDS granule base (x8 ushorts)

  auto stageA = [&](int S) {
    ushort* d = &lds[S & 3][0][0];
    __builtin_amdgcn_global_load_lds((const __attribute__((address_space(1))) void*)(gA0 + S * 32),
        (__attribute__((address_space(3))) void*)(d + lofs), 16, 0, 0);
    __builtin_amdgcn_global_load_lds((const __attribute__((address_space(1))) void*)(gA1 + S * 32),
        (__attribute__((address_space(3))) void*)(d + 4096 + lofs), 16, 0, 0);
  };
  auto stageB = [&](int S) {
    ushort* d = &lds[S & 3][1][0];
    __builtin_amdgcn_global_load_lds((const __attribute__((address_space(1))) void*)(gB0 + S * 32),
        (__attribute__((address_space(3))) void*)(d + lofs), 16, 0, 0);
    __builtin_amdgcn_global_load_lds((const __attribute__((address_space(1))) void*)(gB1 + S * 32),
        (__attribute__((address_space(3))) void*)(d + 4096 + lofs), 16, 0, 0);
  };
  // swizzled fragment read: logical (row, gq) lives at physical granule gq ^ ((row>>1)&3)
  auto frag = [&](const ushort* lb, int row) -> bf16x8 {
    return *(const bf16x8*)(lb + row * 32 + ((gq ^ ((row >> 1) & 3)) << 3));
  };

  f32x4 acc[8][4] = {};
  bf16x8 bF[4];   // B frags of the current K-tile, read at mq=0, reused at mq=1

  // phase: K-tile t, M-quadrant mq (rows wr+mq*64 .. +63). stg: tile to stage (-1 none),
  // stgA: stage A-half (else B). wn: counted vmcnt before closing barrier (-1 none).
  auto phase = [&](int t, int mq, int stg, bool stgA, int wn) {
    const ushort* lA = &lds[t & 3][0][0];
    const ushort* lB = &lds[t & 3][1][0];
    bf16x8 aQ[4];
#pragma unroll
    for (int m = 0; m < 4; ++m) aQ[m] = frag(lA, wr + mq * 64 + m * 16 + fr);
    if (mq == 0) {
#pragma unroll
      for (int n = 0; n < 4; ++n) bF[n] = frag(lB, wc + n * 16 + fr);
    }
    if (stg >= 0) { if (stgA) stageA(stg); else stageB(stg); }
    BAR();
    asm volatile("s_waitcnt lgkmcnt(0)" ::: "memory");
    __builtin_amdgcn_s_setprio(1);
#pragma unroll
    for (int m = 0; m < 4; ++m)
#pragma unroll
      for (int n = 0; n < 4; ++n)
        acc[mq * 4 + m][n] =
            __builtin_amdgcn_mfma_f32_16x16x32_bf16(aQ[m], bF[n], acc[mq * 4 + m][n], 0, 0, 0);
    __builtin_amdgcn_s_setprio(0);
    if (wn == 8)      asm volatile("s_waitcnt vmcnt(8)" ::: "memory");
    else if (wn == 4) asm volatile("s_waitcnt vmcnt(4)" ::: "memory");
    else if (wn == 0) asm volatile("s_waitcnt vmcnt(0)" ::: "memory");
    BAR();
  };

  // ---- prologue: stage tiles 0,1,2 (12 loads); vmcnt(8) lands tile 0 ----
  stageA(0); stageB(0); stageA(1); stageB(1); stageA(2); stageB(2);
  asm volatile("s_waitcnt vmcnt(8)" ::: "memory");
  BAR();

  const int NIT = NK >> 1;
  int j = 0;
  for (; j < NIT - 2; ++j) {
    const int u = 2 * j;
    phase(u,     0, u + 3, true,  -1);
    phase(u,     1, u + 3, false,  8);
    phase(u + 1, 0, u + 4, true,  -1);
    phase(u + 1, 1, u + 4, false,  8);
  }
  {  // j = NIT-2: stage only tile NK-1
    const int u = 2 * j;
    phase(u,     0, u + 3, true,  -1);
    phase(u,     1, u + 3, false,  8);
    phase(u + 1, 0, -1,    true,  -1);
    phase(u + 1, 1, -1,    false,  4);
    ++j;
  }
  {  // j = NIT-1: no staging
    const int u = 2 * j;
    phase(u,     0, -1, true,  -1);
    phase(u,     1, -1, false,  0);
    phase(u + 1, 0, -1, true,  -1);
    phase(u + 1, 1, -1, false, -1);
  }

  // ---- epilogue ----
  const int r0 = bm * 256 + wr + (gq << 2);
  const int c0 = bn * 256 + wc + fr;
#pragma unroll
  for (int m = 0; m < 8; ++m) {
    if constexpr (EPI == 0) {
#pragma unroll
      for (int j2 = 0; j2 < 4; ++j2) {
        size_t ro = (size_t)(r0 + m * 16 + j2) * ldc + c0;
#pragma unroll
        for (int n = 0; n < 4; ++n)
          C[ro + n * 16] = f2bf(acc[m][n][j2]);
      }
    } else {
      // Fused activation: interleaved cols (2k = mag_k, 2k+1 = phase_k);
      // adjacent cols sit in adjacent lanes -> shfl_xor(1) pairs them.
#pragma unroll
      for (int n = 0; n < 4; ++n) {
        const int col = c0 + n * 16;
        const bool valid = col < ODIM;
        const float bs = valid ? bias[(col >> 1) + (col & 1) * KP] : 0.0f;
        const bool isPhase = (col & 1);
#pragma unroll
        for (int j2 = 0; j2 < 4; ++j2) {
          float v = acc[m][n][j2] + bs;
          float pv = __shfl_xor(v, 1);
          float hm = isPhase ? pv : v;
          float hp = isPhase ? v : pv;
          float mag = fminf(fast_exp(hm), 100.0f);
          float outv = isPhase ? mag * fast_sin(hp) : mag * fast_cos(hp);
          if (col < ncol)
            C[(size_t)(r0 + m * 16 + j2) * ldc + col] = valid ? f2bf(outv) : (ushort)0;
        }
      }
    }
  }
}

// ---------------- overlap-add + envelope + crop (4 samples/thread) ----------------
// Interior envelope is exactly 1.5 (Hann^2 OLA at 75% overlap); edges computed inline.
__global__ void k_oa(const ushort* __restrict__ frames, float* __restrict__ out) {
  int u = blockIdx.x * 256 + threadIdx.x;       // 16 * 262144 groups of 4 samples
  int b  = u >> 18;
  int g  = u & 262143;
  int s  = (g << 2) + PADC;
  int t0 = s >> 8;
  int nb = s & 255;                             // <= 252, so the 4 samples share q-blocks
  float acc[4] = {0.f, 0.f, 0.f, 0.f};
  bool interior = (t0 >= 3) && (t0 < TFRM);
  float env[4];
#pragma unroll
  for (int j = 0; j < 4; ++j) env[j] = interior ? 1.5f : 0.0f;
#pragma unroll
  for (int q = 0; q < 4; ++q) {
    int t = t0 - q;
    if (t >= 0 && t < TFRM) {
      int n = nb + (q << 8);
      ushort4 v = *(const ushort4*)(frames + (((size_t)(b << 12) + t) << 10) + n);
      acc[0] += bf2f(v.x); acc[1] += bf2f(v.y); acc[2] += bf2f(v.z); acc[3] += bf2f(v.w);
      if (!interior) {
#pragma unroll
        for (int j = 0; j < 4; ++j) {
          float w = 0.5f - 0.5f * __builtin_amdgcn_cosf((float)(n + j) * (1.0f / 1024.0f));
          env[j] += w * w;
        }
      }
    }
  }
  float4 o;
  o.x = acc[0] / env[0]; o.y = acc[1] / env[1];
  o.z = acc[2] / env[2]; o.w = acc[3] / env[3];
  *(float4*)(out + (size_t)u * 4) = o;
}

// ---------------- launch ----------------
extern "C" void kernel_launch(void* const* d_in, const int* in_sizes, int n_in,
                              void* d_out, int out_size, void* d_ws, size_t ws_size,
                              hipStream_t stream) {
  const float* x    = (const float*)d_in[0];
  const float* W    = (const float*)d_in[1];
  const float* bias = (const float*)d_in[2];
  float* out = (float*)d_out;
  char* ws = (char*)d_ws;

  // ws layout (bytes):
  //   [0, 134217728)            x_bf16 (dead after GEMM1)  ALIASED WITH frames
  //   [134217728, 135528448)    Wp bf16 [1280][512] (column-permuted, zero-padded)
  //   [135528448, 137887744)    BasisT bf16 [1024][1152] (interleaved layout)
  //   [137887744, 288882688)    h bf16 [65536][1152] (post-activation)
  ushort* xbf    = (ushort*)(ws + 0);
  ushort* frames = (ushort*)(ws + 0);
  ushort* Wp     = (ushort*)(ws + 134217728);
  ushort* bas    = (ushort*)(ws + 135528448);
  ushort* h      = (ushort*)(ws + 137887744);

  k_prep_x<<<8192, 256, 0, stream>>>((const float4*)x, (ushort4*)xbf, (MROWS * DIM) / 4);
  k_prep_w<<<(WROWS * DIM) / 256, 256, 0, stream>>>(W, Wp);
  k_basis<<<NFFT, 256, 0, stream>>>(bas);

  // GEMM1 + fused activation: h[65536][<1152] = act( xbf . Wp^T + bias ), N padded to 1280
  k_gemm<1><<<(MROWS / 256) * (WROWS / 256), 512, 0, stream>>>(
      xbf, DIM, Wp, DIM, h, NPAD, WROWS / 256, DIM / 32, NPAD, bias);

  // GEMM2: frames[65536][1024] = h[65536][1152] . BasisT^T
  k_gemm<0><<<(MROWS / 256) * (NFFT / 256), 512, 0, stream>>>(
      h, NPAD, bas, NPAD, frames, NFFT, NFFT / 256, NPAD / 32, NFFT, nullptr);

  // overlap-add, envelope normalize, crop
  k_oa<<<(BATCH * OUTLEN) / 1024, 256, 0, stream>>>(frames, out);
}

// Round 8
// 330.779 us; speedup vs baseline: 1.1423x; 1.1423x over previous
//
#include <hip/hip_runtime.h>
#include <hip/hip_bf16.h>
#include <math.h>

// ---------------- constants ----------------
#define BATCH   16
#define TFRM    4096          // frames per batch (= L)
#define DIM     512
#define NFFT    1024
#define HOP     256
#define PADC    384           // (WIN-HOP)/2
#define MROWS   (BATCH*TFRM)  // 65536
#define OUTLEN  1048576       // per-batch output samples
#define TWO_PI_OVER_N 0.006135923151542565f  // 2*pi/1024
#define INV_TWO_PI    0.15915494309189535f   // 1/(2*pi)

typedef __bf16 bf16x8 __attribute__((ext_vector_type(8)));
typedef float  f32x4  __attribute__((ext_vector_type(4)));

__device__ __forceinline__ ushort f2bf(float f) {
  union { float f; unsigned u; } v; v.f = f;
  unsigned u = v.u;
  unsigned r = (u + 0x7FFFu + ((u >> 16) & 1u)) >> 16;
  return (ushort)r;
}
__device__ __forceinline__ float bf2f(ushort h) {
  union { unsigned u; float f; } v; v.u = ((unsigned)h) << 16;
  return v.f;
}
// HW transcendentals (single VALU op each; v_sin/v_cos take revolutions).
__device__ __forceinline__ float fast_sin(float x) { return __builtin_amdgcn_sinf(x * INV_TWO_PI); }
__device__ __forceinline__ float fast_cos(float x) { return __builtin_amdgcn_cosf(x * INV_TWO_PI); }
__device__ __forceinline__ float fast_exp(float x) { return __builtin_amdgcn_exp2f(x * 1.4426950408889634f); }

#define BAR() do { asm volatile("" ::: "memory"); __builtin_amdgcn_s_barrier(); \
                   asm volatile("" ::: "memory"); } while (0)

// ---------------- prep: x fp32 -> bf16, fused Nyquist GEMV ----------------
// One wave per row: convert the 512 fp32 to bf16, and compute
// s512[row] = min(exp(x.W[512]+b[512]),100)*cos(x.W[1025]+b[1025]) / 1024.
__global__ void k_prep_x(const float* __restrict__ x, const float* __restrict__ W,
                         const float* __restrict__ bias,
                         ushort* __restrict__ xbf, float* __restrict__ s512) {
  const int row  = blockIdx.x * 4 + (threadIdx.x >> 6);
  const int lane = threadIdx.x & 63;
  const float* xr = x + (size_t)row * DIM + lane * 8;
  float4 v0 = *(const float4*)xr;
  float4 v1 = *(const float4*)(xr + 4);
  ushort4 u0, u1;
  u0.x = f2bf(v0.x); u0.y = f2bf(v0.y); u0.z = f2bf(v0.z); u0.w = f2bf(v0.w);
  u1.x = f2bf(v1.x); u1.y = f2bf(v1.y); u1.z = f2bf(v1.z); u1.w = f2bf(v1.w);
  ushort* xo = xbf + (size_t)row * DIM + lane * 8;
  *(ushort4*)xo = u0;
  *(ushort4*)(xo + 4) = u1;
  const float* w0 = W + 512 * DIM + lane * 8;    // mag row k=512
  const float* w1 = W + 1025 * DIM + lane * 8;   // phase row k=512
  float4 a0 = *(const float4*)w0, a1 = *(const float4*)(w0 + 4);
  float4 b0 = *(const float4*)w1, b1 = *(const float4*)(w1 + 4);
  float sm = v0.x*a0.x + v0.y*a0.y + v0.z*a0.z + v0.w*a0.w
           + v1.x*a1.x + v1.y*a1.y + v1.z*a1.z + v1.w*a1.w;
  float sp = v0.x*b0.x + v0.y*b0.y + v0.z*b0.z + v0.w*b0.w
           + v1.x*b1.x + v1.y*b1.y + v1.z*b1.z + v1.w*b1.w;
#pragma unroll
  for (int off = 32; off; off >>= 1) {
    sm += __shfl_down(sm, off);
    sp += __shfl_down(sp, off);
  }
  if (lane == 0) {
    float mag = fminf(fast_exp(sm + bias[512]), 100.0f);
    s512[row] = mag * fast_cos(sp + bias[1025]) * (1.0f / 1024.0f);
  }
}

// ---------------- prep: W fp32 -> bf16 interleaved [1024][512]
// Row j: j=2k -> orig mag row k (k=0..511); j=2k+1 -> orig phase row 513+k.
// (Nyquist rows 512 & 1025 excluded — handled by k_prep_x's fused GEMV.)
__global__ void k_prep_w(const float* __restrict__ W, ushort* __restrict__ o) {
  int i = blockIdx.x * 256 + threadIdx.x;          // over 1024*512
  int r = i >> 9;
  int c = i & 511;
  int orig = (r >> 1) + (r & 1) * 513;
  o[i] = f2bf(W[orig * DIM + c]);
}

// ---------------- basis: BasE/BasO [512 rows][512 K] bf16, row r -> n=r+1 ----------------
// E_st[n] = ( a0 + 2*sum_{k=1..511} a_k cos(2*pi*k*n/1024) ) / 1024
// O_st[n] = (      2*sum_{k=1..511} b_k sin(2*pi*k*n/1024) ) / 1024
// (row n=512 of BasO is auto-zero: sin(pi*k)=0.)
__global__ void k_basis(ushort* __restrict__ basE, ushort* __restrict__ basO) {
  int r = blockIdx.x;                              // 0..511
  int n = r + 1;
  for (int k = threadIdx.x; k < 512; k += 256) {
    float e, o;
    if (k == 0) { e = 1.0f / 1024.0f; o = 0.0f; }
    else {
      int ph = (k * n) & 1023;                     // exact integer phase reduction
      float ang = (float)ph * TWO_PI_OVER_N;
      e = 2.0f * cosf(ang) * (1.0f / 1024.0f);
      o = 2.0f * sinf(ang) * (1.0f / 1024.0f);
    }
    basE[r * 512 + k] = f2bf(e);
    basO[r * 512 + k] = f2bf(o);
  }
}

// ---------------- GEMM: C[m][n] = sum_k A[m][k]*Bt[n][k]  (bf16 in, fp32 acc)
// Core schedule identical to round 7 (256x256 tile, BK=32, 8 waves, ring-4 LDS,
// fine phases, counted vmcnt, granule-XOR swizzle, XCD-chunked block swizzle).
// nsplit>0: blocks with bid>=nsplit switch to the (A2,Bt2,C2) problem (fused
// E/O pair of GEMMs in one launch). EPI=1: ISTFT-head activation epilogue,
// de-interleaved stores: a_k -> C (h_a), b_k -> C2 (h_b), both stride ldc.
template<int EPI>
__global__ __launch_bounds__(512, 2) void k_gemm(const ushort* A, const ushort* A2, int lda,
                                                 const ushort* Bt, const ushort* Bt2, int ldb,
                                                 ushort* C, ushort* C2, int ldc,
                                                 int nbn, int NK, int nsplit,
                                                 const float* __restrict__ bias) {
  __shared__ ushort lds[4][2][8192];
  const int tid  = threadIdx.x;
  const int cpx  = gridDim.x >> 3;
  int bid = (blockIdx.x & 7) * cpx + (blockIdx.x >> 3);   // XCD-chunked
  if (nsplit > 0 && bid >= nsplit) { A = A2; Bt = Bt2; C = C2; bid -= nsplit; }
  const int bm   = bid / nbn;
  const int bn   = bid - bm * nbn;
  const int lane = tid & 63;
  const int wv   = tid >> 6;
  const int wr   = (wv >> 2) * 128;
  const int wc   = (wv & 3) * 64;
  const int fr   = lane & 15;
  const int gq   = lane >> 4;

  const int swz  = ((tid & 3) ^ ((tid >> 3) & 3)) << 3;
  const ushort* gA0 = A  + (size_t)(bm * 256 + (tid >> 2)) * lda + swz;
  const ushort* gA1 = gA0 + (size_t)128 * lda;
  const ushort* gB0 = Bt + (size_t)(bn * 256 + (tid >> 2)) * ldb + swz;
  const ushort* gB1 = gB0 + (size_t)128 * ldb;
  const int lofs = (tid & 448) * 8;

  auto stageA = [&](int S) {
    ushort* d = &lds[S & 3][0][0];
    __builtin_amdgcn_global_load_lds((const __attribute__((address_space(1))) void*)(gA0 + S * 32),
        (__attribute__((address_space(3))) void*)(d + lofs), 16, 0, 0);
    __builtin_amdgcn_global_load_lds((const __attribute__((address_space(1))) void*)(gA1 + S * 32),
        (__attribute__((address_space(3))) void*)(d + 4096 + lofs), 16, 0, 0);
  };
  auto stageB = [&](int S) {
    ushort* d = &lds[S & 3][1][0];
    __builtin_amdgcn_global_load_lds((const __attribute__((address_space(1))) void*)(gB0 + S * 32),
        (__attribute__((address_space(3))) void*)(d + lofs), 16, 0, 0);
    __builtin_amdgcn_global_load_lds((const __attribute__((address_space(1))) void*)(gB1 + S * 32),
        (__attribute__((address_space(3))) void*)(d + 4096 + lofs), 16, 0, 0);
  };
  auto frag = [&](const ushort* lb, int row) -> bf16x8 {
    return *(const bf16x8*)(lb + row * 32 + ((gq ^ ((row >> 1) & 3)) << 3));
  };

  f32x4 acc[8][4] = {};
  bf16x8 bF[4];

  auto phase = [&](int t, int mq, int stg, bool stgA, int wn) {
    const ushort* lA = &lds[t & 3][0][0];
    const ushort* lB = &lds[t & 3][1][0];
    bf16x8 aQ[4];
#pragma unroll
    for (int m = 0; m < 4; ++m) aQ[m] = frag(lA, wr + mq * 64 + m * 16 + fr);
    if (mq == 0) {
#pragma unroll
      for (int n = 0; n < 4; ++n) bF[n] = frag(lB, wc + n * 16 + fr);
    }
    if (stg >= 0) { if (stgA) stageA(stg); else stageB(stg); }
    BAR();
    asm volatile("s_waitcnt lgkmcnt(0)" ::: "memory");
    __builtin_amdgcn_s_setprio(1);
#pragma unroll
    for (int m = 0; m < 4; ++m)
#pragma unroll
      for (int n = 0; n < 4; ++n)
        acc[mq * 4 + m][n] =
            __builtin_amdgcn_mfma_f32_16x16x32_bf16(aQ[m], bF[n], acc[mq * 4 + m][n], 0, 0, 0);
    __builtin_amdgcn_s_setprio(0);
    if (wn == 8)      asm volatile("s_waitcnt vmcnt(8)" ::: "memory");
    else if (wn == 4) asm volatile("s_waitcnt vmcnt(4)" ::: "memory");
    else if (wn == 0) asm volatile("s_waitcnt vmcnt(0)" ::: "memory");
    BAR();
  };

  stageA(0); stageB(0); stageA(1); stageB(1); stageA(2); stageB(2);
  asm volatile("s_waitcnt vmcnt(8)" ::: "memory");
  BAR();

  const int NIT = NK >> 1;
  int j = 0;
  for (; j < NIT - 2; ++j) {
    const int u = 2 * j;
    phase(u,     0, u + 3, true,  -1);
    phase(u,     1, u + 3, false,  8);
    phase(u + 1, 0, u + 4, true,  -1);
    phase(u + 1, 1, u + 4, false,  8);
  }
  {
    const int u = 2 * j;
    phase(u,     0, u + 3, true,  -1);
    phase(u,     1, u + 3, false,  8);
    phase(u + 1, 0, -1,    true,  -1);
    phase(u + 1, 1, -1,    false,  4);
    ++j;
  }
  {
    const int u = 2 * j;
    phase(u,     0, -1, true,  -1);
    phase(u,     1, -1, false,  0);
    phase(u + 1, 0, -1, true,  -1);
    phase(u + 1, 1, -1, false, -1);
  }

  // ---- epilogue ----
  const int r0 = bm * 256 + wr + (gq << 2);
  const int c0 = bn * 256 + wc + fr;
#pragma unroll
  for (int m = 0; m < 8; ++m) {
    if constexpr (EPI == 0) {
#pragma unroll
      for (int j2 = 0; j2 < 4; ++j2) {
        size_t ro = (size_t)(r0 + m * 16 + j2) * ldc + c0;
#pragma unroll
        for (int n = 0; n < 4; ++n)
          C[ro + n * 16] = f2bf(acc[m][n][j2]);
      }
    } else {
      // Fused activation, de-interleaved store: col 2k = mag_k -> a_k into C (h_a),
      // col 2k+1 = phase_k -> b_k into C2 (h_b). shfl_xor(1) pairs adjacent lanes.
#pragma unroll
      for (int n = 0; n < 4; ++n) {
        const int col = c0 + n * 16;                 // 0..1023, all valid
        const int kk  = col >> 1;
        const bool isPhase = (col & 1);
        const float bs = bias[isPhase ? 513 + kk : kk];
        ushort* dst = (isPhase ? C2 : C);
#pragma unroll
        for (int j2 = 0; j2 < 4; ++j2) {
          float v = acc[m][n][j2] + bs;
          float pv = __shfl_xor(v, 1);
          float hm = isPhase ? pv : v;
          float hp = isPhase ? v : pv;
          float mag = fminf(fast_exp(hm), 100.0f);
          float outv = isPhase ? mag * fast_sin(hp) : mag * fast_cos(hp);
          dst[(size_t)(r0 + m * 16 + j2) * ldc + kk] = f2bf(outv);
        }
      }
    }
  }
}

// ---------------- overlap-add: reconstruct frames from E/O + Nyquist, window,
// mirror, envelope normalize, crop. frames[n] = win[n]*(E_st[n] + (-1)^n*s512 -+ O_st[n]),
// n<=512 uses '-', n>512 mirrors to n'=1024-n with '+'. win[0]=0 kills n=0.
__global__ void k_oa(const ushort* __restrict__ E, const ushort* __restrict__ O,
                     const float* __restrict__ s512, float* __restrict__ out) {
  int u = blockIdx.x * 256 + threadIdx.x;       // 16 * 1048576 samples
  int b  = u >> 20;
  int sp = u & (OUTLEN - 1);
  int s  = sp + PADC;
  int t0 = s >> 8;
  int nb = s & 255;
  float acc = 0.0f;
  bool interior = (t0 >= 3) && (t0 < TFRM);
  float env = interior ? 1.5f : 0.0f;
#pragma unroll
  for (int q = 0; q < 4; ++q) {
    int t = t0 - q;
    if (t >= 0 && t < TFRM) {
      int n = nb + (q << 8);
      float w = 0.5f - 0.5f * __builtin_amdgcn_cosf((float)n * (1.0f / 1024.0f));
      if (!interior) env += w * w;
      if (n > 0) {
        size_t base = (((size_t)(b << 12) + t) << 9);      // *(TFRM stride 512)
        float sv = s512[(b << 12) + t];
        float par = (n & 1) ? -sv : sv;
        float d;
        if (n <= 512) {
          int idx = n - 1;
          d = bf2f(E[base + idx]) - bf2f(O[base + idx]) + par;
        } else {
          int idx = 1023 - n;
          d = bf2f(E[base + idx]) + bf2f(O[base + idx]) + par;
        }
        acc += w * d;
      }
    }
  }
  out[u] = acc / env;
}

// ---------------- launch ----------------
extern "C" void kernel_launch(void* const* d_in, const int* in_sizes, int n_in,
                              void* d_out, int out_size, void* d_ws, size_t ws_size,
                              hipStream_t stream) {
  const float* x    = (const float*)d_in[0];
  const float* W    = (const float*)d_in[1];
  const float* bias = (const float*)d_in[2];
  float* out = (float*)d_out;
  char* ws = (char*)d_ws;

  // ws layout (bytes):
  //   [0, 67108864)             xbf bf16 [65536][512]  (dead after GEMM1)  ALIASED WITH E
  //   [67108864, 134217728)     h_a bf16 [65536][512]  (a_k = mag*cos)
  //   [134217728, 201326592)    h_b bf16 [65536][512]  (b_k = mag*sin)
  //   [201326592, 268435456)    O bf16 [65536][512]
  //   [268435456, 269484032)    Wp bf16 [1024][512] (interleaved pairs, no Nyquist)
  //   [269484032, 270008320)    BasE bf16 [512][512]
  //   [270008320, 270532608)    BasO bf16 [512][512]
  //   [270532608, 270794752)    s512 fp32 [65536]  (a_512/1024 per row)
  ushort* xbf  = (ushort*)(ws + 0);
  ushort* Ebuf = (ushort*)(ws + 0);
  ushort* h_a  = (ushort*)(ws + 67108864);
  ushort* h_b  = (ushort*)(ws + 134217728);
  ushort* Obuf = (ushort*)(ws + 201326592);
  ushort* Wp   = (ushort*)(ws + 268435456);
  ushort* basE = (ushort*)(ws + 269484032);
  ushort* basO = (ushort*)(ws + 270008320);
  float*  s512 = (float*) (ws + 270532608);

  k_prep_x<<<MROWS / 4, 256, 0, stream>>>(x, W, bias, xbf, s512);
  k_prep_w<<<(1024 * 512) / 256, 256, 0, stream>>>(W, Wp);
  k_basis<<<512, 256, 0, stream>>>(basE, basO);

  // GEMM1 + fused activation: h_a/h_b[65536][512] from xbf[65536][512] . Wp^T, N=1024
  k_gemm<1><<<1024, 512, 0, stream>>>(xbf, nullptr, DIM, Wp, nullptr, DIM,
                                      h_a, h_b, 512, 4, 16, 0, bias);

  // GEMM2 (fused pair): E = h_a . BasE^T ; O = h_b . BasO^T   (each 65536x512x512)
  k_gemm<0><<<1024, 512, 0, stream>>>(h_a, h_b, 512, basE, basO, 512,
                                      Ebuf, Obuf, 512, 2, 16, 512, nullptr);

  // overlap-add, windowing, mirror reconstruction, envelope normalize, crop
  k_oa<<<(BATCH * OUTLEN) / 256, 256, 0, stream>>>(Ebuf, Obuf, s512, out);
}

// Round 9
// 314.022 us; speedup vs baseline: 1.2032x; 1.0534x over previous
//
#include <hip/hip_runtime.h>
#include <hip/hip_bf16.h>
#include <math.h>

// ---------------- constants ----------------
#define BATCH   16
#define TFRM    4096          // frames per batch (= L)
#define DIM     512
#define NFFT    1024
#define HOP     256
#define PADC    384           // (WIN-HOP)/2
#define MROWS   (BATCH*TFRM)  // 65536
#define OUTLEN  1048576       // per-batch output samples
#define ESTR    520           // E/O row stride (ushorts): col n stored at idx n, 16B-aligned rows
#define TWO_PI_OVER_N 0.006135923151542565f  // 2*pi/1024
#define INV_TWO_PI    0.15915494309189535f   // 1/(2*pi)

typedef __bf16 bf16x8 __attribute__((ext_vector_type(8)));
typedef float  f32x4  __attribute__((ext_vector_type(4)));

__device__ __forceinline__ ushort f2bf(float f) {
  union { float f; unsigned u; } v; v.f = f;
  unsigned u = v.u;
  unsigned r = (u + 0x7FFFu + ((u >> 16) & 1u)) >> 16;
  return (ushort)r;
}
__device__ __forceinline__ float bf2f(ushort h) {
  union { unsigned u; float f; } v; v.u = ((unsigned)h) << 16;
  return v.f;
}
// HW transcendentals (single VALU op each; v_sin/v_cos take revolutions).
__device__ __forceinline__ float fast_sin(float x) { return __builtin_amdgcn_sinf(x * INV_TWO_PI); }
__device__ __forceinline__ float fast_cos(float x) { return __builtin_amdgcn_cosf(x * INV_TWO_PI); }
__device__ __forceinline__ float fast_exp(float x) { return __builtin_amdgcn_exp2f(x * 1.4426950408889634f); }

// ---------------- prep: x fp32 -> bf16, fused Nyquist GEMV ----------------
// One wave per row: convert the 512 fp32 to bf16, and compute
// s512[row] = min(exp(x.W[512]+b[512]),100)*cos(x.W[1025]+b[1025]) / 1024.
__global__ void k_prep_x(const float* __restrict__ x, const float* __restrict__ W,
                         const float* __restrict__ bias,
                         ushort* __restrict__ xbf, float* __restrict__ s512) {
  const int row  = blockIdx.x * 4 + (threadIdx.x >> 6);
  const int lane = threadIdx.x & 63;
  const float* xr = x + (size_t)row * DIM + lane * 8;
  float4 v0 = *(const float4*)xr;
  float4 v1 = *(const float4*)(xr + 4);
  ushort4 u0, u1;
  u0.x = f2bf(v0.x); u0.y = f2bf(v0.y); u0.z = f2bf(v0.z); u0.w = f2bf(v0.w);
  u1.x = f2bf(v1.x); u1.y = f2bf(v1.y); u1.z = f2bf(v1.z); u1.w = f2bf(v1.w);
  ushort* xo = xbf + (size_t)row * DIM + lane * 8;
  *(ushort4*)xo = u0;
  *(ushort4*)(xo + 4) = u1;
  const float* w0 = W + 512 * DIM + lane * 8;    // mag row k=512
  const float* w1 = W + 1025 * DIM + lane * 8;   // phase row k=512
  float4 a0 = *(const float4*)w0, a1 = *(const float4*)(w0 + 4);
  float4 b0 = *(const float4*)w1, b1 = *(const float4*)(w1 + 4);
  float sm = v0.x*a0.x + v0.y*a0.y + v0.z*a0.z + v0.w*a0.w
           + v1.x*a1.x + v1.y*a1.y + v1.z*a1.z + v1.w*a1.w;
  float sp = v0.x*b0.x + v0.y*b0.y + v0.z*b0.z + v0.w*b0.w
           + v1.x*b1.x + v1.y*b1.y + v1.z*b1.z + v1.w*b1.w;
#pragma unroll
  for (int off = 32; off; off >>= 1) {
    sm += __shfl_down(sm, off);
    sp += __shfl_down(sp, off);
  }
  if (lane == 0) {
    float mag = fminf(fast_exp(sm + bias[512]), 100.0f);
    s512[row] = mag * fast_cos(sp + bias[1025]) * (1.0f / 1024.0f);
  }
}

// ---------------- prep: W fp32 -> bf16 interleaved [1024][512]
// Row j: j=2k -> orig mag row k (k=0..511); j=2k+1 -> orig phase row 513+k.
// (Nyquist rows 512 & 1025 excluded — handled by k_prep_x's fused GEMV.)
__global__ void k_prep_w(const float* __restrict__ W, ushort* __restrict__ o) {
  int i = blockIdx.x * 256 + threadIdx.x;          // over 1024*512
  int r = i >> 9;
  int c = i & 511;
  int orig = (r >> 1) + (r & 1) * 513;
  o[i] = f2bf(W[orig * DIM + c]);
}

// ---------------- basis: BasE/BasO [512 rows][512 K] bf16, row r -> n=r+1 ----------------
// E_st[n] = ( a0 + 2*sum_{k=1..511} a_k cos(2*pi*k*n/1024) ) / 1024
// O_st[n] = (      2*sum_{k=1..511} b_k sin(2*pi*k*n/1024) ) / 1024
__global__ void k_basis(ushort* __restrict__ basE, ushort* __restrict__ basO) {
  int r = blockIdx.x;                              // 0..511
  int n = r + 1;
  for (int k = threadIdx.x; k < 512; k += 256) {
    float e, o;
    if (k == 0) { e = 1.0f / 1024.0f; o = 0.0f; }
    else {
      int ph = (k * n) & 1023;                     // exact integer phase reduction
      float ang = (float)ph * TWO_PI_OVER_N;
      e = 2.0f * cosf(ang) * (1.0f / 1024.0f);
      o = 2.0f * sinf(ang) * (1.0f / 1024.0f);
    }
    basE[r * 512 + k] = f2bf(e);
    basO[r * 512 + k] = f2bf(o);
  }
}

// ---------------- GEMM (m97 structure): C[m][n] = sum_k A[m][k]*Bt[n][k], bf16 in, fp32 acc
// 128x128 tile, BK=32, 4 waves (2x2 of 64x64), ring-2 LDS (32 KiB -> multiple blocks/CU,
// implicit inter-block overlap hides the barrier drain), global_load_lds w16 staging.
// Granule-XOR swizzle (physical granule = logical ^ (row&3)), realized by permuting the
// GLOBAL source granule at staging and XOR-ing at ds_read — both fold into per-thread
// constants (zero instruction cost), cutting the 8-way LDS bank conflict to 4-way.
// XCD-chunked block swizzle. nsplit>0: blocks with bid>=nsplit run the (A2,Bt2,C2) problem.
// EPI=1: ISTFT-head activation epilogue, de-interleaved stores (a_k->C, b_k->C2, stride ldc).
// EPI=0: store at col+1 with row stride ldc(=520); first problem folds (-1)^n*s512[row].
template<int EPI>
__global__ __launch_bounds__(256) void k_gemm(const ushort* A, const ushort* A2, int lda,
                                              const ushort* Bt, const ushort* Bt2, int ldb,
                                              ushort* C, ushort* C2, int ldc,
                                              int nbn, int NK, int nsplit,
                                              const float* __restrict__ bias,
                                              const float* __restrict__ s512) {
  __shared__ __align__(16) ushort lds[2][2][128 * 32];
  const int tid  = threadIdx.x;
  const int cpx  = gridDim.x >> 3;
  int bid  = (blockIdx.x & 7) * cpx + (blockIdx.x >> 3);   // XCD-chunked
  bool second = false;
  if (nsplit > 0 && bid >= nsplit) { second = true; A = A2; Bt = Bt2; C = C2; bid -= nsplit; }
  const int bm   = bid / nbn;
  const int bn   = bid - bm * nbn;
  const int lane = tid & 63;
  const int wv   = tid >> 6;
  const int wr   = (wv >> 1) * 64;
  const int wc   = (wv & 1) * 64;
  const int lr   = lane & 15;
  const int gx   = ((lane >> 4) ^ (lane & 3)) << 3;   // swizzled read granule (per-lane const)

  f32x4 acc[4][4] = {};

  const int swz = ((tid & 3) ^ ((tid >> 2) & 3)) << 3; // inverse-swizzled source granule
  auto stage = [&](const ushort* __restrict__ g, int ld, int row0, int k0, ushort* l) {
#pragma unroll
    for (int p = 0; p < 2; ++p) {
      int i = tid + p * 256;
      const ushort* gp = g + (size_t)(row0 + (i >> 2)) * ld + k0 + swz;
      ushort* lp = l + ((i >> 6) << 9);   // wave-uniform LDS base; HW scatters lane*16B
      __builtin_amdgcn_global_load_lds(
          (const __attribute__((address_space(1))) void*)gp,
          (__attribute__((address_space(3))) void*)lp, 16, 0, 0);
    }
  };

  stage(A,  lda, bm * 128, 0, &lds[0][0][0]);
  stage(Bt, ldb, bn * 128, 0, &lds[0][1][0]);
  asm volatile("s_waitcnt vmcnt(0)" ::: "memory");
  __syncthreads();

  for (int t = 0; t < NK; ++t) {
    const int cur = t & 1;
    if (t + 1 < NK) {
      stage(A,  lda, bm * 128, (t + 1) << 5, &lds[cur ^ 1][0][0]);
      stage(Bt, ldb, bn * 128, (t + 1) << 5, &lds[cur ^ 1][1][0]);
    }
    const ushort* lA = &lds[cur][0][0];
    const ushort* lB = &lds[cur][1][0];
    bf16x8 aF[4], bF[4];
#pragma unroll
    for (int m = 0; m < 4; ++m)
      aF[m] = *(const bf16x8*)(lA + (wr + m * 16 + lr) * 32 + gx);
#pragma unroll
    for (int n = 0; n < 4; ++n)
      bF[n] = *(const bf16x8*)(lB + (wc + n * 16 + lr) * 32 + gx);
#pragma unroll
    for (int m = 0; m < 4; ++m)
#pragma unroll
      for (int n = 0; n < 4; ++n)
        acc[m][n] = __builtin_amdgcn_mfma_f32_16x16x32_bf16(aF[m], bF[n], acc[m][n], 0, 0, 0);
    asm volatile("s_waitcnt vmcnt(0)" ::: "memory");
    __syncthreads();
  }

  const int r0 = bm * 128 + wr + ((lane >> 4) << 2);
  const int c0 = bn * 128 + wc + lr;
#pragma unroll
  for (int m = 0; m < 4; ++m) {
    if constexpr (EPI == 0) {
      // Store E/O at col+1 (stride ldc=520). E problem folds the Nyquist rank-1 term:
      // E''[r][n] = E[r][n] + (-1)^n * s512[r]  (n = c+1; c even -> n odd -> -sv).
      float4 sv4 = {0.f, 0.f, 0.f, 0.f};
      if (!second) sv4 = *(const float4*)(s512 + r0 + m * 16);
#pragma unroll
      for (int j = 0; j < 4; ++j) {
        size_t ro = (size_t)(r0 + m * 16 + j) * ldc;
        float sv = ((const float*)&sv4)[j];
#pragma unroll
        for (int n = 0; n < 4; ++n) {
          int c = c0 + n * 16;
          float par = second ? 0.0f : ((c & 1) ? sv : -sv);
          C[ro + c + 1] = f2bf(acc[m][n][j] + par);
        }
      }
    } else {
      // Fused activation, de-interleaved: col 2k = mag_k -> a_k into C (h_a),
      // col 2k+1 = phase_k -> b_k into C2 (h_b). shfl_xor(1) pairs adjacent lanes.
#pragma unroll
      for (int n = 0; n < 4; ++n) {
        const int col = c0 + n * 16;                 // 0..1023, all valid
        const int kk  = col >> 1;
        const bool isPhase = (col & 1);
        const float bs = bias[isPhase ? 513 + kk : kk];
        ushort* dst = (isPhase ? C2 : C);
#pragma unroll
        for (int j = 0; j < 4; ++j) {
          float v = acc[m][n][j] + bs;
          float pv = __shfl_xor(v, 1);
          float hm = isPhase ? pv : v;
          float hp = isPhase ? v : pv;
          float mag = fminf(fast_exp(hm), 100.0f);
          float outv = isPhase ? mag * fast_sin(hp) : mag * fast_cos(hp);
          dst[(size_t)(r0 + m * 16 + j) * ldc + kk] = f2bf(outv);
        }
      }
    }
  }
}

// ---------------- overlap-add (4 samples/thread, vectorized) ----------------
// frames[n] = win[n]*(E''[n] -+ O[n]); n<=512 direct ('-'), n>512 mirrors to 1024-n ('+').
// Nyquist term pre-folded into E''. Interior envelope exactly 1.5.
__global__ void k_oa(const ushort* __restrict__ E, const ushort* __restrict__ O,
                     float* __restrict__ out) {
  int u = blockIdx.x * 256 + threadIdx.x;       // 16 * 262144 groups of 4 samples
  int b  = u >> 18;
  int g  = u & 262143;
  int s  = (g << 2) + PADC;
  int t0 = s >> 8;
  int nb = s & 255;                             // multiple of 4
  float acc[4] = {0.f, 0.f, 0.f, 0.f};
  bool interior = (t0 >= 3) && (t0 < TFRM);
  float env[4];
#pragma unroll
  for (int j = 0; j < 4; ++j) env[j] = interior ? 1.5f : 0.0f;
#pragma unroll
  for (int q = 0; q < 4; ++q) {
    int t = t0 - q;
    if (t < 0 || t >= TFRM) continue;
    int n = nb + (q << 8);                      // multiple of 4, in [0, 1020]
    size_t base = ((size_t)(b << 12) + t) * ESTR;
    float w[4];
#pragma unroll
    for (int j = 0; j < 4; ++j) {
      w[j] = 0.5f - 0.5f * __builtin_amdgcn_cosf((float)(n + j) * (1.0f / 1024.0f));
      if (!interior) env[j] += w[j] * w[j];
    }
    float d[4];
    if (n + 3 <= 512) {                         // direct (n==0: w[0]=0 kills idx-0 garbage)
      ushort4 e = *(const ushort4*)(E + base + n);
      ushort4 o = *(const ushort4*)(O + base + n);
      d[0] = bf2f(e.x) - bf2f(o.x); d[1] = bf2f(e.y) - bf2f(o.y);
      d[2] = bf2f(e.z) - bf2f(o.z); d[3] = bf2f(e.w) - bf2f(o.w);
    } else if (n >= 516) {                      // mirror: idx 1024-n descending
      int m2 = 1024 - n;                        // multiple of 4, in [4, 508]
      ushort4 e0 = *(const ushort4*)(E + base + m2);
      ushort4 e1 = *(const ushort4*)(E + base + m2 - 4);
      ushort4 o0 = *(const ushort4*)(O + base + m2);
      ushort4 o1 = *(const ushort4*)(O + base + m2 - 4);
      d[0] = bf2f(e0.x) + bf2f(o0.x); d[1] = bf2f(e1.w) + bf2f(o1.w);
      d[2] = bf2f(e1.z) + bf2f(o1.z); d[3] = bf2f(e1.y) + bf2f(o1.y);
    } else {                                    // n == 512 straddle
      d[0] = bf2f(E[base + 512]) - bf2f(O[base + 512]);
      d[1] = bf2f(E[base + 511]) + bf2f(O[base + 511]);
      d[2] = bf2f(E[base + 510]) + bf2f(O[base + 510]);
      d[3] = bf2f(E[base + 509]) + bf2f(O[base + 509]);
    }
#pragma unroll
    for (int j = 0; j < 4; ++j) acc[j] += w[j] * d[j];
  }
  float4 o4;
  o4.x = acc[0] / env[0]; o4.y = acc[1] / env[1];
  o4.z = acc[2] / env[2]; o4.w = acc[3] / env[3];
  *(float4*)(out + (size_t)u * 4) = o4;
}

// ---------------- launch ----------------
extern "C" void kernel_launch(void* const* d_in, const int* in_sizes, int n_in,
                              void* d_out, int out_size, void* d_ws, size_t ws_size,
                              hipStream_t stream) {
  const float* x    = (const float*)d_in[0];
  const float* W    = (const float*)d_in[1];
  const float* bias = (const float*)d_in[2];
  float* out = (float*)d_out;
  char* ws = (char*)d_ws;

  // ws layout (bytes):
  //   [0, 68157440)             xbf bf16 [65536][512] (dead after GEMM1)  ALIASED WITH E''
  //   [68157440, 135266304)     h_a bf16 [65536][512]  (a_k = mag*cos)
  //   [135266304, 202375168)    h_b bf16 [65536][512]  (b_k = mag*sin)
  //   [202375168, 270532608)    O  bf16 [65536][520]
  //   [270532608, 271581184)    Wp bf16 [1024][512] (interleaved pairs, no Nyquist)
  //   [271581184, 272105472)    BasE bf16 [512][512]
  //   [272105472, 272629760)    BasO bf16 [512][512]
  //   [272629760, 272891904)    s512 fp32 [65536]
  ushort* xbf  = (ushort*)(ws + 0);
  ushort* Epp  = (ushort*)(ws + 0);
  ushort* h_a  = (ushort*)(ws + 68157440);
  ushort* h_b  = (ushort*)(ws + 135266304);
  ushort* Obuf = (ushort*)(ws + 202375168);
  ushort* Wp   = (ushort*)(ws + 270532608);
  ushort* basE = (ushort*)(ws + 271581184);
  ushort* basO = (ushort*)(ws + 272105472);
  float*  s512 = (float*) (ws + 272629760);

  k_prep_x<<<MROWS / 4, 256, 0, stream>>>(x, W, bias, xbf, s512);
  k_prep_w<<<(1024 * 512) / 256, 256, 0, stream>>>(W, Wp);
  k_basis<<<512, 256, 0, stream>>>(basE, basO);

  // GEMM1 + fused activation: h_a/h_b[65536][512] = act( xbf[65536][512] . Wp^T ), N=1024
  k_gemm<1><<<(MROWS / 128) * 8, 256, 0, stream>>>(
      xbf, nullptr, DIM, Wp, nullptr, DIM, h_a, h_b, 512, 8, 16, 0, bias, nullptr);

  // GEMM2 (fused pair): E'' = h_a . BasE^T (+Nyquist fold) ; O = h_b . BasO^T
  k_gemm<0><<<2 * (MROWS / 128) * 4, 256, 0, stream>>>(
      h_a, h_b, 512, basE, basO, 512, Epp, Obuf, ESTR, 4, 16, (MROWS / 128) * 4,
      nullptr, s512);

  // overlap-add, windowing, mirror reconstruction, envelope normalize, crop
  k_oa<<<(BATCH * OUTLEN) / 1024, 256, 0, stream>>>(Epp, Obuf, out);
}

// Round 10
// 310.792 us; speedup vs baseline: 1.2157x; 1.0104x over previous
//
#include <hip/hip_runtime.h>
#include <hip/hip_bf16.h>
#include <math.h>

// ---------------- constants ----------------
#define BATCH   16
#define TFRM    4096          // frames per batch (= L)
#define DIM     512
#define NFFT    1024
#define HOP     256
#define PADC    384           // (WIN-HOP)/2
#define MROWS   (BATCH*TFRM)  // 65536
#define OUTLEN  1048576       // per-batch output samples
#define ESTR    520           // E/O row stride (ushorts): col n stored at idx n, 16B-aligned rows
#define TWO_PI_OVER_N 0.006135923151542565f  // 2*pi/1024
#define INV_TWO_PI    0.15915494309189535f   // 1/(2*pi)

typedef __bf16 bf16x8 __attribute__((ext_vector_type(8)));
typedef float  f32x4  __attribute__((ext_vector_type(4)));

__device__ __forceinline__ ushort f2bf(float f) {
  union { float f; unsigned u; } v; v.f = f;
  unsigned u = v.u;
  unsigned r = (u + 0x7FFFu + ((u >> 16) & 1u)) >> 16;
  return (ushort)r;
}
__device__ __forceinline__ float bf2f(ushort h) {
  union { unsigned u; float f; } v; v.u = ((unsigned)h) << 16;
  return v.f;
}
// HW transcendentals (single VALU op each; v_sin/v_cos take revolutions).
__device__ __forceinline__ float fast_sin(float x) { return __builtin_amdgcn_sinf(x * INV_TWO_PI); }
__device__ __forceinline__ float fast_cos(float x) { return __builtin_amdgcn_cosf(x * INV_TWO_PI); }
__device__ __forceinline__ float fast_exp(float x) { return __builtin_amdgcn_exp2f(x * 1.4426950408889634f); }

// ---------------- prep: x fp32 -> bf16, fused Nyquist GEMV ----------------
// One wave per row: convert the 512 fp32 to bf16, and compute
// s512[row] = min(exp(x.W[512]+b[512]),100)*cos(x.W[1025]+b[1025]) / 1024.
__global__ void k_prep_x(const float* __restrict__ x, const float* __restrict__ W,
                         const float* __restrict__ bias,
                         ushort* __restrict__ xbf, float* __restrict__ s512) {
  const int row  = blockIdx.x * 4 + (threadIdx.x >> 6);
  const int lane = threadIdx.x & 63;
  const float* xr = x + (size_t)row * DIM + lane * 8;
  float4 v0 = *(const float4*)xr;
  float4 v1 = *(const float4*)(xr + 4);
  ushort4 u0, u1;
  u0.x = f2bf(v0.x); u0.y = f2bf(v0.y); u0.z = f2bf(v0.z); u0.w = f2bf(v0.w);
  u1.x = f2bf(v1.x); u1.y = f2bf(v1.y); u1.z = f2bf(v1.z); u1.w = f2bf(v1.w);
  ushort* xo = xbf + (size_t)row * DIM + lane * 8;
  *(ushort4*)xo = u0;
  *(ushort4*)(xo + 4) = u1;
  const float* w0 = W + 512 * DIM + lane * 8;    // mag row k=512
  const float* w1 = W + 1025 * DIM + lane * 8;   // phase row k=512
  float4 a0 = *(const float4*)w0, a1 = *(const float4*)(w0 + 4);
  float4 b0 = *(const float4*)w1, b1 = *(const float4*)(w1 + 4);
  float sm = v0.x*a0.x + v0.y*a0.y + v0.z*a0.z + v0.w*a0.w
           + v1.x*a1.x + v1.y*a1.y + v1.z*a1.z + v1.w*a1.w;
  float sp = v0.x*b0.x + v0.y*b0.y + v0.z*b0.z + v0.w*b0.w
           + v1.x*b1.x + v1.y*b1.y + v1.z*b1.z + v1.w*b1.w;
#pragma unroll
  for (int off = 32; off; off >>= 1) {
    sm += __shfl_down(sm, off);
    sp += __shfl_down(sp, off);
  }
  if (lane == 0) {
    float mag = fminf(fast_exp(sm + bias[512]), 100.0f);
    s512[row] = mag * fast_cos(sp + bias[1025]) * (1.0f / 1024.0f);
  }
}

// ---------------- prep: W fp32 -> bf16 interleaved [1024][512]
// Row j: j=2k -> orig mag row k (k=0..511); j=2k+1 -> orig phase row 513+k.
// (Nyquist rows 512 & 1025 excluded — handled by k_prep_x's fused GEMV.)
__global__ void k_prep_w(const float* __restrict__ W, ushort* __restrict__ o) {
  int i = blockIdx.x * 256 + threadIdx.x;          // over 1024*512
  int r = i >> 9;
  int c = i & 511;
  int orig = (r >> 1) + (r & 1) * 513;
  o[i] = f2bf(W[orig * DIM + c]);
}

// ---------------- basis: BasE/BasO [512 rows][512 K] bf16, row r -> n=r+1 ----------------
// E_st[n] = ( a0 + 2*sum_{k=1..511} a_k cos(2*pi*k*n/1024) ) / 1024
// O_st[n] = (      2*sum_{k=1..511} b_k sin(2*pi*k*n/1024) ) / 1024
__global__ void k_basis(ushort* __restrict__ basE, ushort* __restrict__ basO) {
  int r = blockIdx.x;                              // 0..511
  int n = r + 1;
  for (int k = threadIdx.x; k < 512; k += 256) {
    float e, o;
    if (k == 0) { e = 1.0f / 1024.0f; o = 0.0f; }
    else {
      int ph = (k * n) & 1023;                     // exact integer phase reduction
      float ang = (float)ph * TWO_PI_OVER_N;
      e = 2.0f * cosf(ang) * (1.0f / 1024.0f);
      o = 2.0f * sinf(ang) * (1.0f / 1024.0f);
    }
    basE[r * 512 + k] = f2bf(e);
    basO[r * 512 + k] = f2bf(o);
  }
}

// ---------------- GEMM (m97 structure + ring-3 prefetch): C[m][n] = sum_k A[m][k]*Bt[n][k]
// 128x128 tile, BK=32, 4 waves (2x2 of 64x64), ring of THREE 16 KiB LDS K-tile slots
// (48 KiB -> 3 blocks/CU), prefetch distance 2, counted vmcnt(4) per tile (wait lands
// tile T+1, tile T+2's 4 loads stay in flight) — per-tile stall = load latency minus a
// full tile of compute, while inter-block overlap covers the rest.
// Granule-XOR swizzle: physical granule = logical ^ ((row>>1)&3), realized by permuting
// the GLOBAL source granule at staging and XOR at ds_read — both per-thread constants.
// Bank math: bank = (row&1)<<4 | g<<2 | w, so (row>>1)&3 spreads 16-lane row-columns to
// 2-way (free); round 9's (row&3) left a 4-way conflict (8.4e6 counted).
// XCD-chunked block swizzle. nsplit>0: blocks with bid>=nsplit run the (A2,Bt2,C2) problem.
// EPI=1: ISTFT-head activation epilogue, de-interleaved stores (a_k->C, b_k->C2).
// EPI=0: store at col+1 with row stride ldc(=520); first problem folds (-1)^n*s512[row].
template<int EPI>
__global__ __launch_bounds__(256) void k_gemm(const ushort* A, const ushort* A2, int lda,
                                              const ushort* Bt, const ushort* Bt2, int ldb,
                                              ushort* C, ushort* C2, int ldc,
                                              int nbn, int NK, int nsplit,
                                              const float* __restrict__ bias,
                                              const float* __restrict__ s512) {
  __shared__ __align__(16) ushort lds[3][2][128 * 32];
  const int tid  = threadIdx.x;
  const int cpx  = gridDim.x >> 3;
  int bid  = (blockIdx.x & 7) * cpx + (blockIdx.x >> 3);   // XCD-chunked
  bool second = false;
  if (nsplit > 0 && bid >= nsplit) { second = true; A = A2; Bt = Bt2; C = C2; bid -= nsplit; }
  const int bm   = bid / nbn;
  const int bn   = bid - bm * nbn;
  const int lane = tid & 63;
  const int wv   = tid >> 6;
  const int wr   = (wv >> 1) * 64;
  const int wc   = (wv & 1) * 64;
  const int lr   = lane & 15;
  const int gx   = ((lane >> 4) ^ ((lane >> 1) & 3)) << 3; // swizzled read granule

  f32x4 acc[4][4] = {};

  const int swz = ((tid & 3) ^ ((tid >> 3) & 3)) << 3;     // inverse-swizzled source granule
  auto stage = [&](const ushort* __restrict__ g, int ld, int row0, int k0, ushort* l) {
#pragma unroll
    for (int p = 0; p < 2; ++p) {
      int i = tid + p * 256;
      const ushort* gp = g + (size_t)(row0 + (i >> 2)) * ld + k0 + swz;
      ushort* lp = l + ((i >> 6) << 9);   // wave-uniform LDS base; HW scatters lane*16B
      __builtin_amdgcn_global_load_lds(
          (const __attribute__((address_space(1))) void*)gp,
          (__attribute__((address_space(3))) void*)lp, 16, 0, 0);
    }
  };

  // prologue: stage tiles 0 and 1; land tile 0 (tile 1's 4 loads stay in flight)
  stage(A,  lda, bm * 128, 0,  &lds[0][0][0]);
  stage(Bt, ldb, bn * 128, 0,  &lds[0][1][0]);
  stage(A,  lda, bm * 128, 32, &lds[1][0][0]);
  stage(Bt, ldb, bn * 128, 32, &lds[1][1][0]);
  asm volatile("s_waitcnt vmcnt(4)" ::: "memory");
  __syncthreads();

  int sl = 0;                                              // slot of tile t
  for (int t = 0; t < NK; ++t) {
    if (t + 2 < NK) {
      const int psl = (sl >= 1) ? sl - 1 : 2;              // (sl+2)%3
      stage(A,  lda, bm * 128, (t + 2) << 5, &lds[psl][0][0]);
      stage(Bt, ldb, bn * 128, (t + 2) << 5, &lds[psl][1][0]);
    }
    const ushort* lA = &lds[sl][0][0];
    const ushort* lB = &lds[sl][1][0];
    bf16x8 aF[4], bF[4];
#pragma unroll
    for (int m = 0; m < 4; ++m)
      aF[m] = *(const bf16x8*)(lA + (wr + m * 16 + lr) * 32 + gx);
#pragma unroll
    for (int n = 0; n < 4; ++n)
      bF[n] = *(const bf16x8*)(lB + (wc + n * 16 + lr) * 32 + gx);
#pragma unroll
    for (int m = 0; m < 4; ++m)
#pragma unroll
      for (int n = 0; n < 4; ++n)
        acc[m][n] = __builtin_amdgcn_mfma_f32_16x16x32_bf16(aF[m], bF[n], acc[m][n], 0, 0, 0);
    // counted wait: land tile t+1; leave tile t+2's 4 loads in flight
    if (t + 2 < NK)      asm volatile("s_waitcnt vmcnt(4)" ::: "memory");
    else if (t + 2 == NK) asm volatile("s_waitcnt vmcnt(0)" ::: "memory");
    if (t + 1 < NK) __syncthreads();
    sl = (sl >= 2) ? 0 : sl + 1;
  }

  const int r0 = bm * 128 + wr + ((lane >> 4) << 2);
  const int c0 = bn * 128 + wc + lr;
#pragma unroll
  for (int m = 0; m < 4; ++m) {
    if constexpr (EPI == 0) {
      // Store E/O at col+1 (stride ldc=520). E problem folds the Nyquist rank-1 term:
      // E''[r][n] = E[r][n] + (-1)^n * s512[r]  (n = c+1; c even -> n odd -> -sv).
      float4 sv4 = {0.f, 0.f, 0.f, 0.f};
      if (!second) sv4 = *(const float4*)(s512 + r0 + m * 16);
#pragma unroll
      for (int j = 0; j < 4; ++j) {
        size_t ro = (size_t)(r0 + m * 16 + j) * ldc;
        float sv = ((const float*)&sv4)[j];
#pragma unroll
        for (int n = 0; n < 4; ++n) {
          int c = c0 + n * 16;
          float par = second ? 0.0f : ((c & 1) ? sv : -sv);
          C[ro + c + 1] = f2bf(acc[m][n][j] + par);
        }
      }
    } else {
      // Fused activation, de-interleaved: col 2k = mag_k -> a_k into C (h_a),
      // col 2k+1 = phase_k -> b_k into C2 (h_b). shfl_xor(1) pairs adjacent lanes.
#pragma unroll
      for (int n = 0; n < 4; ++n) {
        const int col = c0 + n * 16;                 // 0..1023, all valid
        const int kk  = col >> 1;
        const bool isPhase = (col & 1);
        const float bs = bias[isPhase ? 513 + kk : kk];
        ushort* dst = (isPhase ? C2 : C);
#pragma unroll
        for (int j = 0; j < 4; ++j) {
          float v = acc[m][n][j] + bs;
          float pv = __shfl_xor(v, 1);
          float hm = isPhase ? pv : v;
          float hp = isPhase ? v : pv;
          float mag = fminf(fast_exp(hm), 100.0f);
          float outv = isPhase ? mag * fast_sin(hp) : mag * fast_cos(hp);
          dst[(size_t)(r0 + m * 16 + j) * ldc + kk] = f2bf(outv);
        }
      }
    }
  }
}

// ---------------- overlap-add (4 samples/thread, vectorized) ----------------
// frames[n] = win[n]*(E''[n] -+ O[n]); n<=512 direct ('-'), n>512 mirrors to 1024-n ('+').
// Nyquist term pre-folded into E''. Interior envelope exactly 1.5.
__global__ void k_oa(const ushort* __restrict__ E, const ushort* __restrict__ O,
                     float* __restrict__ out) {
  int u = blockIdx.x * 256 + threadIdx.x;       // 16 * 262144 groups of 4 samples
  int b  = u >> 18;
  int g  = u & 262143;
  int s  = (g << 2) + PADC;
  int t0 = s >> 8;
  int nb = s & 255;                             // multiple of 4
  float acc[4] = {0.f, 0.f, 0.f, 0.f};
  bool interior = (t0 >= 3) && (t0 < TFRM);
  float env[4];
#pragma unroll
  for (int j = 0; j < 4; ++j) env[j] = interior ? 1.5f : 0.0f;
#pragma unroll
  for (int q = 0; q < 4; ++q) {
    int t = t0 - q;
    if (t < 0 || t >= TFRM) continue;
    int n = nb + (q << 8);                      // multiple of 4, in [0, 1020]
    size_t base = ((size_t)(b << 12) + t) * ESTR;
    float w[4];
#pragma unroll
    for (int j = 0; j < 4; ++j) {
      w[j] = 0.5f - 0.5f * __builtin_amdgcn_cosf((float)(n + j) * (1.0f / 1024.0f));
      if (!interior) env[j] += w[j] * w[j];
    }
    float d[4];
    if (n + 3 <= 512) {                         // direct (n==0: w[0]=0 kills idx-0 garbage)
      ushort4 e = *(const ushort4*)(E + base + n);
      ushort4 o = *(const ushort4*)(O + base + n);
      d[0] = bf2f(e.x) - bf2f(o.x); d[1] = bf2f(e.y) - bf2f(o.y);
      d[2] = bf2f(e.z) - bf2f(o.z); d[3] = bf2f(e.w) - bf2f(o.w);
    } else if (n >= 516) {                      // mirror: idx 1024-n descending
      int m2 = 1024 - n;                        // multiple of 4, in [4, 508]
      ushort4 e0 = *(const ushort4*)(E + base + m2);
      ushort4 e1 = *(const ushort4*)(E + base + m2 - 4);
      ushort4 o0 = *(const ushort4*)(O + base + m2);
      ushort4 o1 = *(const ushort4*)(O + base + m2 - 4);
      d[0] = bf2f(e0.x) + bf2f(o0.x); d[1] = bf2f(e1.w) + bf2f(o1.w);
      d[2] = bf2f(e1.z) + bf2f(o1.z); d[3] = bf2f(e1.y) + bf2f(o1.y);
    } else {                                    // n == 512 straddle
      d[0] = bf2f(E[base + 512]) - bf2f(O[base + 512]);
      d[1] = bf2f(E[base + 511]) + bf2f(O[base + 511]);
      d[2] = bf2f(E[base + 510]) + bf2f(O[base + 510]);
      d[3] = bf2f(E[base + 509]) + bf2f(O[base + 509]);
    }
#pragma unroll
    for (int j = 0; j < 4; ++j) acc[j] += w[j] * d[j];
  }
  float4 o4;
  o4.x = acc[0] / env[0]; o4.y = acc[1] / env[1];
  o4.z = acc[2] / env[2]; o4.w = acc[3] / env[3];
  *(float4*)(out + (size_t)u * 4) = o4;
}

// ---------------- launch ----------------
extern "C" void kernel_launch(void* const* d_in, const int* in_sizes, int n_in,
                              void* d_out, int out_size, void* d_ws, size_t ws_size,
                              hipStream_t stream) {
  const float* x    = (const float*)d_in[0];
  const float* W    = (const float*)d_in[1];
  const float* bias = (const float*)d_in[2];
  float* out = (float*)d_out;
  char* ws = (char*)d_ws;

  // ws layout (bytes):
  //   [0, 68157440)             xbf bf16 [65536][512] (dead after GEMM1)  ALIASED WITH E''
  //   [68157440, 135266304)     h_a bf16 [65536][512]  (a_k = mag*cos)
  //   [135266304, 202375168)    h_b bf16 [65536][512]  (b_k = mag*sin)
  //   [202375168, 270532608)    O  bf16 [65536][520]
  //   [270532608, 271581184)    Wp bf16 [1024][512] (interleaved pairs, no Nyquist)
  //   [271581184, 272105472)    BasE bf16 [512][512]
  //   [272105472, 272629760)    BasO bf16 [512][512]
  //   [272629760, 272891904)    s512 fp32 [65536]
  ushort* xbf  = (ushort*)(ws + 0);
  ushort* Epp  = (ushort*)(ws + 0);
  ushort* h_a  = (ushort*)(ws + 68157440);
  ushort* h_b  = (ushort*)(ws + 135266304);
  ushort* Obuf = (ushort*)(ws + 202375168);
  ushort* Wp   = (ushort*)(ws + 270532608);
  ushort* basE = (ushort*)(ws + 271581184);
  ushort* basO = (ushort*)(ws + 272105472);
  float*  s512 = (float*) (ws + 272629760);

  k_prep_x<<<MROWS / 4, 256, 0, stream>>>(x, W, bias, xbf, s512);
  k_prep_w<<<(1024 * 512) / 256, 256, 0, stream>>>(W, Wp);
  k_basis<<<512, 256, 0, stream>>>(basE, basO);

  // GEMM1 + fused activation: h_a/h_b[65536][512] = act( xbf[65536][512] . Wp^T ), N=1024
  k_gemm<1><<<(MROWS / 128) * 8, 256, 0, stream>>>(
      xbf, nullptr, DIM, Wp, nullptr, DIM, h_a, h_b, 512, 8, 16, 0, bias, nullptr);

  // GEMM2 (fused pair): E'' = h_a . BasE^T (+Nyquist fold) ; O = h_b . BasO^T
  k_gemm<0><<<2 * (MROWS / 128) * 4, 256, 0, stream>>>(
      h_a, h_b, 512, basE, basO, 512, Epp, Obuf, ESTR, 4, 16, (MROWS / 128) * 4,
      nullptr, s512);

  // overlap-add, windowing, mirror reconstruction, envelope normalize, crop
  k_oa<<<(BATCH * OUTLEN) / 1024, 256, 0, stream>>>(Epp, Obuf, out);
}

// Round 11
// 294.091 us; speedup vs baseline: 1.2848x; 1.0568x over previous
//
#include <hip/hip_runtime.h>
#include <hip/hip_bf16.h>
#include <math.h>

// ---------------- constants ----------------
#define BATCH   16
#define TFRM    4096          // frames per batch (= L)
#define DIM     512
#define NFFT    1024
#define HOP     256
#define PADC    384           // (WIN-HOP)/2
#define MROWS   (BATCH*TFRM)  // 65536
#define OUTLEN  1048576       // per-batch output samples
#define TWO_PI_OVER_N 0.006135923151542565f  // 2*pi/1024
#define INV_TWO_PI    0.15915494309189535f   // 1/(2*pi)

typedef __bf16 bf16x8 __attribute__((ext_vector_type(8)));
typedef float  f32x4  __attribute__((ext_vector_type(4)));

__device__ __forceinline__ ushort f2bf(float f) {
  union { float f; unsigned u; } v; v.f = f;
  unsigned u = v.u;
  unsigned r = (u + 0x7FFFu + ((u >> 16) & 1u)) >> 16;
  return (ushort)r;
}
__device__ __forceinline__ float bf2f(ushort h) {
  union { unsigned u; float f; } v; v.u = ((unsigned)h) << 16;
  return v.f;
}
// HW transcendentals (single VALU op each; v_sin/v_cos take revolutions).
__device__ __forceinline__ float fast_sin(float x) { return __builtin_amdgcn_sinf(x * INV_TWO_PI); }
__device__ __forceinline__ float fast_cos(float x) { return __builtin_amdgcn_cosf(x * INV_TWO_PI); }
__device__ __forceinline__ float fast_exp(float x) { return __builtin_amdgcn_exp2f(x * 1.4426950408889634f); }
// lane-xor-1 exchange as a single VALU DPP op (quad_perm [1,0,3,2] = 0xB1) —
// replaces __shfl_xor(v,1), which hipcc lowers to ds_swizzle (LDS op + lgkm wait).
__device__ __forceinline__ float dpp_xor1(float v) {
  return __int_as_float(__builtin_amdgcn_update_dpp(
      __float_as_int(v), __float_as_int(v), 0xB1, 0xF, 0xF, false));
}

// ---------------- prep: x fp32 -> bf16, fused Nyquist GEMV ----------------
// One wave per row: convert the 512 fp32 to bf16, and compute
// s512[row] = min(exp(x.W[512]+b[512]),100)*cos(x.W[1025]+b[1025]) / 1024.
__global__ void k_prep_x(const float* __restrict__ x, const float* __restrict__ W,
                         const float* __restrict__ bias,
                         ushort* __restrict__ xbf, float* __restrict__ s512) {
  const int row  = blockIdx.x * 4 + (threadIdx.x >> 6);
  const int lane = threadIdx.x & 63;
  const float* xr = x + (size_t)row * DIM + lane * 8;
  float4 v0 = *(const float4*)xr;
  float4 v1 = *(const float4*)(xr + 4);
  ushort4 u0, u1;
  u0.x = f2bf(v0.x); u0.y = f2bf(v0.y); u0.z = f2bf(v0.z); u0.w = f2bf(v0.w);
  u1.x = f2bf(v1.x); u1.y = f2bf(v1.y); u1.z = f2bf(v1.z); u1.w = f2bf(v1.w);
  ushort* xo = xbf + (size_t)row * DIM + lane * 8;
  *(ushort4*)xo = u0;
  *(ushort4*)(xo + 4) = u1;
  const float* w0 = W + 512 * DIM + lane * 8;    // mag row k=512
  const float* w1 = W + 1025 * DIM + lane * 8;   // phase row k=512
  float4 a0 = *(const float4*)w0, a1 = *(const float4*)(w0 + 4);
  float4 b0 = *(const float4*)w1, b1 = *(const float4*)(w1 + 4);
  float sm = v0.x*a0.x + v0.y*a0.y + v0.z*a0.z + v0.w*a0.w
           + v1.x*a1.x + v1.y*a1.y + v1.z*a1.z + v1.w*a1.w;
  float sp = v0.x*b0.x + v0.y*b0.y + v0.z*b0.z + v0.w*b0.w
           + v1.x*b1.x + v1.y*b1.y + v1.z*b1.z + v1.w*b1.w;
#pragma unroll
  for (int off = 32; off; off >>= 1) {
    sm += __shfl_down(sm, off);
    sp += __shfl_down(sp, off);
  }
  if (lane == 0) {
    float mag = fminf(fast_exp(sm + bias[512]), 100.0f);
    s512[row] = mag * fast_cos(sp + bias[1025]) * (1.0f / 1024.0f);
  }
}

// ---------------- prep: W fp32 -> bf16 interleaved [1024][512]
// Row j: j=2k -> orig mag row k (k=0..511); j=2k+1 -> orig phase row 513+k.
__global__ void k_prep_w(const float* __restrict__ W, ushort* __restrict__ o) {
  int i = blockIdx.x * 256 + threadIdx.x;          // over 1024*512
  int r = i >> 9;
  int c = i & 511;
  int orig = (r >> 1) + (r & 1) * 513;
  o[i] = f2bf(W[orig * DIM + c]);
}

// ---------------- basis: BasE/BasO [512 rows][512 K] bf16, row r -> n=r+1 ----------------
__global__ void k_basis(ushort* __restrict__ basE, ushort* __restrict__ basO) {
  int r = blockIdx.x;                              // 0..511
  int n = r + 1;
  for (int k = threadIdx.x; k < 512; k += 256) {
    float e, o;
    if (k == 0) { e = 1.0f / 1024.0f; o = 0.0f; }
    else {
      int ph = (k * n) & 1023;                     // exact integer phase reduction
      float ang = (float)ph * TWO_PI_OVER_N;
      e = 2.0f * cosf(ang) * (1.0f / 1024.0f);
      o = 2.0f * sinf(ang) * (1.0f / 1024.0f);
    }
    basE[r * 512 + k] = f2bf(e);
    basO[r * 512 + k] = f2bf(o);
  }
}

// ---------------- GEMM (m97 structure + ring-3 prefetch + LDS-staged epilogue)
// Main loop identical to round 10 (at its plateau): 128x128 tile, BK=32, 4 waves,
// ring-3 LDS (48 KiB, 3 blocks/CU), prefetch distance 2, counted vmcnt(4),
// granule-XOR swizzle ((row>>1)&3 — conflict-free), XCD-chunked block swizzle.
// EPILOGUE (the former fixed-cost monster: 64 scattered 2B stores + 64 ds_swizzle
// shuffles per thread) now goes through LDS: write bf16 results into a padded LDS
// tile (row stride ≡ 8 mod 32 words -> conflict-free b16 writes), one barrier,
// read back b128 and store ushort8 coalesced. Mag/phase pairing via DPP quad_perm.
// nsplit>0: blocks with bid>=nsplit run the (A2,Bt2,C2) problem.
// EPI=1: activation epilogue, de-interleaved (a_k->C, b_k->C2), ldc=512.
// EPI=0: E/O store UNSHIFTED (C[i] = value for n_st=i+1), first problem folds
//        the Nyquist rank-1 term (-1)^(i+1)*s512[row]; ldc=512.
template<int EPI>
__global__ __launch_bounds__(256) void k_gemm(const ushort* A, const ushort* A2, int lda,
                                              const ushort* Bt, const ushort* Bt2, int ldb,
                                              ushort* C, ushort* C2, int ldc,
                                              int nbn, int NK, int nsplit,
                                              const float* __restrict__ bias,
                                              const float* __restrict__ s512) {
  __shared__ __align__(16) ushort lds[3][2][128 * 32];   // 48 KiB; reused by epilogue
  const int tid  = threadIdx.x;
  const int cpx  = gridDim.x >> 3;
  int bid  = (blockIdx.x & 7) * cpx + (blockIdx.x >> 3);   // XCD-chunked
  bool second = false;
  if (nsplit > 0 && bid >= nsplit) { second = true; A = A2; Bt = Bt2; C = C2; bid -= nsplit; }
  const int bm   = bid / nbn;
  const int bn   = bid - bm * nbn;
  const int lane = tid & 63;
  const int wv   = tid >> 6;
  const int wr   = (wv >> 1) * 64;
  const int wc   = (wv & 1) * 64;
  const int lr   = lane & 15;
  const int gx   = ((lane >> 4) ^ ((lane >> 1) & 3)) << 3; // swizzled read granule

  f32x4 acc[4][4] = {};

  const int swz = ((tid & 3) ^ ((tid >> 3) & 3)) << 3;     // inverse-swizzled source granule
  auto stage = [&](const ushort* __restrict__ g, int ld, int row0, int k0, ushort* l) {
#pragma unroll
    for (int p = 0; p < 2; ++p) {
      int i = tid + p * 256;
      const ushort* gp = g + (size_t)(row0 + (i >> 2)) * ld + k0 + swz;
      ushort* lp = l + ((i >> 6) << 9);   // wave-uniform LDS base; HW scatters lane*16B
      __builtin_amdgcn_global_load_lds(
          (const __attribute__((address_space(1))) void*)gp,
          (__attribute__((address_space(3))) void*)lp, 16, 0, 0);
    }
  };

  // prologue: stage tiles 0 and 1; land tile 0 (tile 1's 4 loads stay in flight)
  stage(A,  lda, bm * 128, 0,  &lds[0][0][0]);
  stage(Bt, ldb, bn * 128, 0,  &lds[0][1][0]);
  stage(A,  lda, bm * 128, 32, &lds[1][0][0]);
  stage(Bt, ldb, bn * 128, 32, &lds[1][1][0]);
  asm volatile("s_waitcnt vmcnt(4)" ::: "memory");
  __syncthreads();

  int sl = 0;                                              // slot of tile t
  for (int t = 0; t < NK; ++t) {
    if (t + 2 < NK) {
      const int psl = (sl >= 1) ? sl - 1 : 2;              // (sl+2)%3
      stage(A,  lda, bm * 128, (t + 2) << 5, &lds[psl][0][0]);
      stage(Bt, ldb, bn * 128, (t + 2) << 5, &lds[psl][1][0]);
    }
    const ushort* lA = &lds[sl][0][0];
    const ushort* lB = &lds[sl][1][0];
    bf16x8 aF[4], bF[4];
#pragma unroll
    for (int m = 0; m < 4; ++m)
      aF[m] = *(const bf16x8*)(lA + (wr + m * 16 + lr) * 32 + gx);
#pragma unroll
    for (int n = 0; n < 4; ++n)
      bF[n] = *(const bf16x8*)(lB + (wc + n * 16 + lr) * 32 + gx);
#pragma unroll
    for (int m = 0; m < 4; ++m)
#pragma unroll
      for (int n = 0; n < 4; ++n)
        acc[m][n] = __builtin_amdgcn_mfma_f32_16x16x32_bf16(aF[m], bF[n], acc[m][n], 0, 0, 0);
    if (t + 2 < NK)      asm volatile("s_waitcnt vmcnt(4)" ::: "memory");
    else if (t + 2 == NK) asm volatile("s_waitcnt vmcnt(0)" ::: "memory");
    if (t + 1 < NK) __syncthreads();
    sl = (sl >= 2) ? 0 : sl + 1;
  }

  // ---- epilogue (LDS-staged, coalesced) ----
  const int rl = wr + ((lane >> 4) << 2);    // local row base of this lane's acc quads
  const int r0 = bm * 128 + rl;              // global row base (s512 lookup)
  ushort* epi = &lds[0][0][0];
  __syncthreads();   // all main-loop LDS reads complete everywhere before overwrite

  if constexpr (EPI == 0) {
    // value(col c) = acc + Nyquist fold (first problem): n_st = c+1; c even -> -sv.
    // LDS tile [128][144] ushort (stride 144 = 72 words ≡ 8 mod 32 -> conflict-free).
#pragma unroll
    for (int m = 0; m < 4; ++m) {
      float4 sv4 = {0.f, 0.f, 0.f, 0.f};
      if (!second) sv4 = *(const float4*)(s512 + r0 + m * 16);
#pragma unroll
      for (int j = 0; j < 4; ++j) {
        float sv = ((const float*)&sv4)[j];
        int row = rl + m * 16 + j;
#pragma unroll
        for (int n = 0; n < 4; ++n) {
          int c = wc + n * 16 + lr;
          float par = second ? 0.0f : ((c & 1) ? sv : -sv);
          epi[row * 144 + c] = f2bf(acc[m][n][j] + par);
        }
      }
    }
    __syncthreads();
#pragma unroll
    for (int i = 0; i < 8; ++i) {
      int row = (tid >> 4) + i * 16;
      int co  = (tid & 15) << 3;
      bf16x8 v = *(const bf16x8*)(epi + row * 144 + co);
      *(bf16x8*)(C + (size_t)(bm * 128 + row) * ldc + bn * 128 + co) = v;
    }
  } else {
    // Activation: interleaved cols (2k=mag_k, 2k+1=phase_k); DPP pairs adjacent lanes.
    // Two LDS tiles [128][80] ushort (stride 80 = 40 words ≡ 8 mod 32 -> conflict-free).
    ushort* tA = epi;
    ushort* tB = epi + 128 * 80;
#pragma unroll
    for (int m = 0; m < 4; ++m) {
#pragma unroll
      for (int n = 0; n < 4; ++n) {
        const int cl  = wc + n * 16 + lr;            // local col 0..127
        const int kk  = (bn * 128 + cl) >> 1;        // global k index
        const bool isPhase = (cl & 1);
        const float bs = bias[isPhase ? 513 + kk : kk];
        ushort* dst = (isPhase ? tB : tA);
        const int kkl = cl >> 1;                     // local k 0..63
#pragma unroll
        for (int j = 0; j < 4; ++j) {
          float v = acc[m][n][j] + bs;
          float pv = dpp_xor1(v);
          float hm = isPhase ? pv : v;
          float hp = isPhase ? v : pv;
          float mag = fminf(fast_exp(hm), 100.0f);
          float outv = isPhase ? mag * fast_sin(hp) : mag * fast_cos(hp);
          dst[(rl + m * 16 + j) * 80 + kkl] = f2bf(outv);
        }
      }
    }
    __syncthreads();
#pragma unroll
    for (int i = 0; i < 4; ++i) {
      int row = (tid >> 3) + i * 32;
      int co  = (tid & 7) << 3;
      size_t go = (size_t)(bm * 128 + row) * ldc + bn * 64 + co;
      bf16x8 va = *(const bf16x8*)(tA + row * 80 + co);
      *(bf16x8*)(C + go) = va;
      bf16x8 vb = *(const bf16x8*)(tB + row * 80 + co);
      *(bf16x8*)(C2 + go) = vb;
    }
  }
}

// ---------------- overlap-add (4 samples/thread, aligned vector loads) ----------------
// E/O unshifted: E[i] = E_st[i+1], stride 512. frames[n] = win[n]*(E_st[n] -+ O_st[n]);
// n<=512 direct ('-'), n>512 mirrors to 1024-n ('+'). Nyquist pre-folded into E.
// Interior envelope exactly 1.5 (Hann^2 OLA at 75% overlap).
__global__ void k_oa(const ushort* __restrict__ E, const ushort* __restrict__ O,
                     float* __restrict__ out) {
  int u = blockIdx.x * 256 + threadIdx.x;       // 16 * 262144 groups of 4 samples
  int b  = u >> 18;
  int g  = u & 262143;
  int s  = (g << 2) + PADC;
  int t0 = s >> 8;
  int nb = s & 255;                             // multiple of 4
  float acc[4] = {0.f, 0.f, 0.f, 0.f};
  bool interior = (t0 >= 3) && (t0 < TFRM);
  float env[4];
#pragma unroll
  for (int j = 0; j < 4; ++j) env[j] = interior ? 1.5f : 0.0f;
#pragma unroll
  for (int q = 0; q < 4; ++q) {
    int t = t0 - q;
    if (t < 0 || t >= TFRM) continue;
    int n = nb + (q << 8);                      // multiple of 4, in [0, 1020]
    size_t base = ((size_t)(b << 12) + t) << 9; // row * 512
    float w[4];
#pragma unroll
    for (int j = 0; j < 4; ++j) {
      w[j] = 0.5f - 0.5f * __builtin_amdgcn_cosf((float)(n + j) * (1.0f / 1024.0f));
      if (!interior) env[j] += w[j] * w[j];
    }
    float d[4];
    if (n <= 508) {                             // direct: d[j] = E[n+j-1] - O[n+j-1]
      ushort4 e1 = *(const ushort4*)(E + base + n);
      ushort4 o1 = *(const ushort4*)(O + base + n);
      if (n >= 4) {
        ushort4 e0 = *(const ushort4*)(E + base + n - 4);
        ushort4 o0 = *(const ushort4*)(O + base + n - 4);
        d[0] = bf2f(e0.w) - bf2f(o0.w);
      } else d[0] = 0.0f;                       // n==0: w[0]=0 anyway
      d[1] = bf2f(e1.x) - bf2f(o1.x);
      d[2] = bf2f(e1.y) - bf2f(o1.y);
      d[3] = bf2f(e1.z) - bf2f(o1.z);
    } else if (n == 512) {                      // straddle: one aligned load at 508
      ushort4 e = *(const ushort4*)(E + base + 508);
      ushort4 o = *(const ushort4*)(O + base + 508);
      d[0] = bf2f(e.w) - bf2f(o.w);             // O_st[512]=0, sign moot
      d[1] = bf2f(e.z) + bf2f(o.z);
      d[2] = bf2f(e.y) + bf2f(o.y);
      d[3] = bf2f(e.x) + bf2f(o.x);
    } else {                                    // n >= 516 mirror: load at 1020-n
      ushort4 e = *(const ushort4*)(E + base + 1020 - n);
      ushort4 o = *(const ushort4*)(O + base + 1020 - n);
      d[0] = bf2f(e.w) + bf2f(o.w);
      d[1] = bf2f(e.z) + bf2f(o.z);
      d[2] = bf2f(e.y) + bf2f(o.y);
      d[3] = bf2f(e.x) + bf2f(o.x);
    }
#pragma unroll
    for (int j = 0; j < 4; ++j) acc[j] += w[j] * d[j];
  }
  float4 o4;
  o4.x = acc[0] / env[0]; o4.y = acc[1] / env[1];
  o4.z = acc[2] / env[2]; o4.w = acc[3] / env[3];
  *(float4*)(out + (size_t)u * 4) = o4;
}

// ---------------- launch ----------------
extern "C" void kernel_launch(void* const* d_in, const int* in_sizes, int n_in,
                              void* d_out, int out_size, void* d_ws, size_t ws_size,
                              hipStream_t stream) {
  const float* x    = (const float*)d_in[0];
  const float* W    = (const float*)d_in[1];
  const float* bias = (const float*)d_in[2];
  float* out = (float*)d_out;
  char* ws = (char*)d_ws;

  // ws layout (bytes):
  //   [0, 67108864)             xbf bf16 [65536][512] (dead after GEMM1)  ALIASED WITH E
  //   [67108864, 134217728)     h_a bf16 [65536][512]  (a_k = mag*cos)
  //   [134217728, 201326592)    h_b bf16 [65536][512]  (b_k = mag*sin)
  //   [201326592, 268435456)    O  bf16 [65536][512]
  //   [268435456, 269484032)    Wp bf16 [1024][512] (interleaved pairs, no Nyquist)
  //   [269484032, 270008320)    BasE bf16 [512][512]
  //   [270008320, 270532608)    BasO bf16 [512][512]
  //   [270532608, 270794752)    s512 fp32 [65536]
  ushort* xbf  = (ushort*)(ws + 0);
  ushort* Epp  = (ushort*)(ws + 0);
  ushort* h_a  = (ushort*)(ws + 67108864);
  ushort* h_b  = (ushort*)(ws + 134217728);
  ushort* Obuf = (ushort*)(ws + 201326592);
  ushort* Wp   = (ushort*)(ws + 268435456);
  ushort* basE = (ushort*)(ws + 269484032);
  ushort* basO = (ushort*)(ws + 270008320);
  float*  s512 = (float*) (ws + 270532608);

  k_prep_x<<<MROWS / 4, 256, 0, stream>>>(x, W, bias, xbf, s512);
  k_prep_w<<<(1024 * 512) / 256, 256, 0, stream>>>(W, Wp);
  k_basis<<<512, 256, 0, stream>>>(basE, basO);

  // GEMM1 + fused activation: h_a/h_b[65536][512] = act( xbf[65536][512] . Wp^T ), N=1024
  k_gemm<1><<<(MROWS / 128) * 8, 256, 0, stream>>>(
      xbf, nullptr, DIM, Wp, nullptr, DIM, h_a, h_b, 512, 8, 16, 0, bias, nullptr);

  // GEMM2 (fused pair): E = h_a . BasE^T (+Nyquist fold) ; O = h_b . BasO^T
  k_gemm<0><<<2 * (MROWS / 128) * 4, 256, 0, stream>>>(
      h_a, h_b, 512, basE, basO, 512, Epp, Obuf, 512, 4, 16, (MROWS / 128) * 4,
      nullptr, s512);

  // overlap-add, windowing, mirror reconstruction, envelope normalize, crop
  k_oa<<<(BATCH * OUTLEN) / 1024, 256, 0, stream>>>(Epp, Obuf, out);
}